// Round 1
// baseline (1972.963 us; speedup 1.0000x reference)
//
#include <hip/hip_runtime.h>

namespace {

constexpr int T_SEQ = 2048;
constexpr int B_SZ  = 512;
constexpr int C_IN  = 8;
constexpr int H_SZ  = 20;

// Broadcast the value of `v` in lane `lane` to all lanes (SGPR result).
__device__ __forceinline__ float rlane(float v, int lane) {
  return __int_as_float(__builtin_amdgcn_readlane(__float_as_int(v), lane));
}

// Broadcast quad slot S to all 4 lanes of each quad (DPP quad_perm).
template<int S>
__device__ __forceinline__ float quad_bcast(float v) {
  return __int_as_float(__builtin_amdgcn_update_dpp(
      __float_as_int(v), __float_as_int(v), S * 0x55, 0xF, 0xF, true));
}

// slot!=2: sigmoid(a)  (cm=-1, am=1, ad=0)
// slot==2: tanh(a)     (cm=-2, am=2, ad=-1), via tanh(x)=2*sigmoid(2x)-1
__device__ __forceinline__ float gate_act(float a, float cm, float am, float ad) {
  float e = __expf(a * cm);
  float s = __builtin_amdgcn_rcpf(1.0f + e);
  return __fmaf_rn(s, am, ad);
}

__device__ __forceinline__ float fast_tanh(float a) {
  float e = __expf(-2.0f * a);
  float s = __builtin_amdgcn_rcpf(1.0f + e);
  return __fmaf_rn(s, 2.0f, -1.0f);
}

// Fetch h[k] given set1 register (valid at lanes 4k, k<16) and
// set2 register (valid at lanes 4q for k=16+q).
#define H_BCAST(ha, hb, k) (((k) < 16) ? rlane((ha), 4 * (k)) : rlane((hb), 4 * ((k) - 16)))

__global__ void __launch_bounds__(64, 1)
lstm2_fused(const float* __restrict__ x,
            const float* __restrict__ Wih0, const float* __restrict__ Whh0,
            const float* __restrict__ bih0, const float* __restrict__ bhh0,
            const float* __restrict__ Wih1, const float* __restrict__ Whh1,
            const float* __restrict__ bih1, const float* __restrict__ bhh1,
            float* __restrict__ out)
{
  const int l  = threadIdx.x;        // 0..63
  const int b  = blockIdx.x;         // batch element
  const int k1 = l >> 2;             // 0..15  (set1 hidden index)
  const int g  = l & 3;              // gate slot: 0=i 1=f 2=g 3=o
  const int k2 = 16 + (k1 & 3);      // 16..19 (set2 hidden index; duplicated across lane groups)
  const int j1 = g * H_SZ + k1;      // gate row, set1
  const int j2 = g * H_SZ + k2;      // gate row, set2

  // ---- stage weights into registers (one-time; tiny vs 2048-step loop) ----
  float wih0a[C_IN], wih0b[C_IN];
  float whh0a[H_SZ], whh0b[H_SZ];
  float wih1a[H_SZ], wih1b[H_SZ];
  float whh1a[H_SZ], whh1b[H_SZ];
#pragma unroll
  for (int c = 0; c < C_IN; ++c) {
    wih0a[c] = Wih0[j1 * C_IN + c];
    wih0b[c] = Wih0[j2 * C_IN + c];
  }
#pragma unroll
  for (int k = 0; k < H_SZ; ++k) {
    whh0a[k] = Whh0[j1 * H_SZ + k];
    whh0b[k] = Whh0[j2 * H_SZ + k];
    wih1a[k] = Wih1[j1 * H_SZ + k];
    wih1b[k] = Wih1[j2 * H_SZ + k];
    whh1a[k] = Whh1[j1 * H_SZ + k];
    whh1b[k] = Whh1[j2 * H_SZ + k];
  }
  const float bias0a = bih0[j1] + bhh0[j1];
  const float bias0b = bih0[j2] + bhh0[j2];
  const float bias1a = bih1[j1] + bhh1[j1];
  const float bias1b = bih1[j2] + bhh1[j2];

  // Branch-free activation constants (slot 2 is tanh, others sigmoid).
  const bool  isg = (g == 2);
  const float cm  = isg ? -2.0f : -1.0f;
  const float am  = isg ?  2.0f :  1.0f;
  const float ad  = isg ? -1.0f :  0.0f;

  // ---- state (zero-init per reference) ----
  float h0a = 0.f, c0a = 0.f, h0b = 0.f, c0b = 0.f;   // layer 0
  float h1a = 0.f, c1a = 0.f, h1b = 0.f, c1b = 0.f;   // layer 1

  // ---- x prefetch, depth 2 (32B/step, wave-uniform address) ----
  const float* xrow = x + b * C_IN;
  float4 xc0 = *(const float4*)(xrow);
  float4 xc1 = *(const float4*)(xrow + 4);
  xrow += B_SZ * C_IN;
  float4 xn0 = *(const float4*)(xrow);
  float4 xn1 = *(const float4*)(xrow + 4);

  float* op = out + b * H_SZ;

  for (int t = 0; t < T_SEQ; ++t) {
    const float xv[C_IN] = {xc0.x, xc0.y, xc0.z, xc0.w, xc1.x, xc1.y, xc1.z, xc1.w};
    xc0 = xn0; xc1 = xn1;
    if (t + 2 < T_SEQ) {               // uniform branch; issue t+2 loads early
      xrow += B_SZ * C_IN;
      xn0 = *(const float4*)(xrow);
      xn1 = *(const float4*)(xrow + 4);
    }

    // ================= layer 0 =================
    float a1e = bias0a, a1o = 0.f, a2e = bias0b, a2o = 0.f;
#pragma unroll
    for (int c = 0; c < C_IN; c += 2) {
      a1e = __fmaf_rn(wih0a[c],     xv[c],     a1e);
      a1o = __fmaf_rn(wih0a[c + 1], xv[c + 1], a1o);
      a2e = __fmaf_rn(wih0b[c],     xv[c],     a2e);
      a2o = __fmaf_rn(wih0b[c + 1], xv[c + 1], a2o);
    }
#pragma unroll
    for (int k = 0; k < H_SZ; k += 2) {
      float hk0 = H_BCAST(h0a, h0b, k);
      float hk1 = H_BCAST(h0a, h0b, k + 1);
      a1e = __fmaf_rn(whh0a[k],     hk0, a1e);
      a1o = __fmaf_rn(whh0a[k + 1], hk1, a1o);
      a2e = __fmaf_rn(whh0b[k],     hk0, a2e);
      a2o = __fmaf_rn(whh0b[k + 1], hk1, a2o);
    }
    float act1 = gate_act(a1e + a1o, cm, am, ad);
    float act2 = gate_act(a2e + a2o, cm, am, ad);
    {
      float iv = quad_bcast<0>(act1), fv = quad_bcast<1>(act1);
      float gv = quad_bcast<2>(act1), ov = quad_bcast<3>(act1);
      c0a = __fmaf_rn(fv, c0a, iv * gv);
      h0a = ov * fast_tanh(c0a);
      iv = quad_bcast<0>(act2); fv = quad_bcast<1>(act2);
      gv = quad_bcast<2>(act2); ov = quad_bcast<3>(act2);
      c0b = __fmaf_rn(fv, c0b, iv * gv);
      h0b = ov * fast_tanh(c0b);
    }

    // ================= layer 1 (input y = fresh layer-0 h) =================
    float p1e = bias1a, p1o = 0.f, p2e = bias1b, p2o = 0.f;
#pragma unroll
    for (int k = 0; k < H_SZ; k += 2) {
      float y0 = H_BCAST(h0a, h0b, k);
      float y1 = H_BCAST(h0a, h0b, k + 1);
      float q0 = H_BCAST(h1a, h1b, k);
      float q1 = H_BCAST(h1a, h1b, k + 1);
      p1e = __fmaf_rn(wih1a[k],     y0, p1e);
      p1o = __fmaf_rn(wih1a[k + 1], y1, p1o);
      p2e = __fmaf_rn(wih1b[k],     y0, p2e);
      p2o = __fmaf_rn(wih1b[k + 1], y1, p2o);
      p1e = __fmaf_rn(whh1a[k],     q0, p1e);
      p1o = __fmaf_rn(whh1a[k + 1], q1, p1o);
      p2e = __fmaf_rn(whh1b[k],     q0, p2e);
      p2o = __fmaf_rn(whh1b[k + 1], q1, p2o);
    }
    act1 = gate_act(p1e + p1o, cm, am, ad);
    act2 = gate_act(p2e + p2o, cm, am, ad);
    {
      float iv = quad_bcast<0>(act1), fv = quad_bcast<1>(act1);
      float gv = quad_bcast<2>(act1), ov = quad_bcast<3>(act1);
      c1a = __fmaf_rn(fv, c1a, iv * gv);
      h1a = ov * fast_tanh(c1a);
      iv = quad_bcast<0>(act2); fv = quad_bcast<1>(act2);
      gv = quad_bcast<2>(act2); ov = quad_bcast<3>(act2);
      c1b = __fmaf_rn(fv, c1b, iv * gv);
      h1b = ov * fast_tanh(c1b);
    }

    // ---- store out[t, b, :] (h of layer 1) ----
    if ((l & 3) == 0) {
      op[k1] = h1a;                    // cols 0..15 from lanes 0,4,...,60
      if (l < 16) op[16 + k1] = h1b;   // cols 16..19 from lanes 0,4,8,12
    }
    op += B_SZ * H_SZ;
  }
}

} // namespace

extern "C" void kernel_launch(void* const* d_in, const int* in_sizes, int n_in,
                              void* d_out, int out_size, void* d_ws, size_t ws_size,
                              hipStream_t stream) {
  const float* x    = (const float*)d_in[0];
  const float* Wih0 = (const float*)d_in[1];
  const float* Whh0 = (const float*)d_in[2];
  const float* bih0 = (const float*)d_in[3];
  const float* bhh0 = (const float*)d_in[4];
  const float* Wih1 = (const float*)d_in[5];
  const float* Whh1 = (const float*)d_in[6];
  const float* bih1 = (const float*)d_in[7];
  const float* bhh1 = (const float*)d_in[8];
  float* out = (float*)d_out;

  hipLaunchKernelGGL(lstm2_fused, dim3(B_SZ), dim3(64), 0, stream,
                     x, Wih0, Whh0, bih0, bhh0, Wih1, Whh1, bih1, bhh1, out);
}

// Round 2
// 1371.109 us; speedup vs baseline: 1.4390x; 1.4390x over previous
//
#include <hip/hip_runtime.h>

namespace {

constexpr int T_SEQ = 2048;
constexpr int B_SZ  = 512;
constexpr int C_IN  = 8;
constexpr int H_SZ  = 20;
constexpr float LOG2E = 1.44269504088896340736f;

// Broadcast lane `lane`'s value to all lanes (SGPR result; lane is a literal).
__device__ __forceinline__ float rlane(float v, int lane) {
  return __int_as_float(__builtin_amdgcn_readlane(__float_as_int(v), lane));
}

// Broadcast quad slot S to all 4 lanes of each quad (DPP quad_perm).
template<int S>
__device__ __forceinline__ float quad_bcast(float v) {
  return __int_as_float(__builtin_amdgcn_update_dpp(
      __float_as_int(v), __float_as_int(v), S * 0x55, 0xF, 0xF, true));
}

// slot!=2: sigmoid(a) = rcp(1+exp2(-a*log2e))
// slot==2: tanh(a)    = 2*rcp(1+exp2(-2a*log2e)) - 1
// cm has log2e pre-folded, so only exp2 (v_exp_f32) is needed.
__device__ __forceinline__ float gate_act(float a, float cm, float am, float ad) {
  float e = __builtin_amdgcn_exp2f(a * cm);
  float s = __builtin_amdgcn_rcpf(1.0f + e);
  return __fmaf_rn(s, am, ad);
}

__device__ __forceinline__ float fast_tanh(float a) {
  float e = __builtin_amdgcn_exp2f(a * (-2.0f * LOG2E));
  float s = __builtin_amdgcn_rcpf(1.0f + e);
  return __fmaf_rn(s, 2.0f, -1.0f);
}

// h[k] broadcast: set1 value valid at lanes 4k (k<16); set2 value (k=16..19)
// valid at lanes 4q, q=k-16 (replicated every 16 lanes, lane 4q works).
#define H_BCAST(ha, hb, k) (((k) < 16) ? rlane((ha), 4 * (k)) : rlane((hb), 4 * ((k) - 16)))

__global__ __attribute__((amdgpu_flat_work_group_size(128, 128),
                          amdgpu_waves_per_eu(1, 1)))
void lstm2_pipe(const float* __restrict__ x,
                const float* __restrict__ Wih0, const float* __restrict__ Whh0,
                const float* __restrict__ bih0, const float* __restrict__ bhh0,
                const float* __restrict__ Wih1, const float* __restrict__ Whh1,
                const float* __restrict__ bih1, const float* __restrict__ bhh1,
                float* __restrict__ out)
{
  // h0 handoff: double-buffered, 20 floats each. Row stride 80 B (16-aligned).
  __shared__ __align__(16) float hbuf[2][H_SZ];

  const int tid = threadIdx.x;
  const int wv  = tid >> 6;          // 0 = layer-0 wave, 1 = layer-1 wave
  const int l   = tid & 63;
  const int b   = blockIdx.x;
  const int k1  = l >> 2;            // 0..15  (set1 hidden index)
  const int g   = l & 3;             // gate slot: 0=i 1=f 2=g 3=o
  const int k2  = 16 + (k1 & 3);     // 16..19 (set2, replicated 4x across wave)
  const int j1  = g * H_SZ + k1;     // gate row, set1
  const int j2  = g * H_SZ + k2;     // gate row, set2

  const bool  isg = (g == 2);
  const float cm  = isg ? (-2.0f * LOG2E) : (-LOG2E);
  const float am  = isg ?  2.0f : 1.0f;
  const float ad  = isg ? -1.0f : 0.0f;

  if (wv == 0) {
    // ================= layer-0 producer wave =================
    float wiha[C_IN], wihb[C_IN], whha[H_SZ], whhb[H_SZ];
#pragma unroll
    for (int c = 0; c < C_IN; ++c) {
      wiha[c] = Wih0[j1 * C_IN + c];
      wihb[c] = Wih0[j2 * C_IN + c];
    }
#pragma unroll
    for (int k = 0; k < H_SZ; ++k) {
      whha[k] = Whh0[j1 * H_SZ + k];
      whhb[k] = Whh0[j2 * H_SZ + k];
    }
    const float ba = bih0[j1] + bhh0[j1];
    const float bb = bih0[j2] + bhh0[j2];

    float ha = 0.f, ca = 0.f, hb = 0.f, cb = 0.f;

    // x prefetch depth 2 (wave-uniform 32 B rows)
    const float* xrow = x + b * C_IN;
    float4 xc0 = *(const float4*)(xrow);
    float4 xc1 = *(const float4*)(xrow + 4);
    xrow += B_SZ * C_IN;
    float4 xn0 = *(const float4*)(xrow);
    float4 xn1 = *(const float4*)(xrow + 4);

    for (int n = 0; n <= T_SEQ; ++n) {
      if (n < T_SEQ) {
        const float xv[C_IN] = {xc0.x, xc0.y, xc0.z, xc0.w,
                                xc1.x, xc1.y, xc1.z, xc1.w};
        xc0 = xn0; xc1 = xn1;
        if (n + 2 < T_SEQ) {
          xrow += B_SZ * C_IN;
          xn0 = *(const float4*)(xrow);
          xn1 = *(const float4*)(xrow + 4);
        }

        float a1e = ba, a1o = 0.f, a2e = bb, a2o = 0.f;
#pragma unroll
        for (int c = 0; c < C_IN; c += 2) {
          a1e = __fmaf_rn(wiha[c],     xv[c],     a1e);
          a1o = __fmaf_rn(wiha[c + 1], xv[c + 1], a1o);
          a2e = __fmaf_rn(wihb[c],     xv[c],     a2e);
          a2o = __fmaf_rn(wihb[c + 1], xv[c + 1], a2o);
        }
#pragma unroll
        for (int k = 0; k < H_SZ; k += 2) {
          float h0 = H_BCAST(ha, hb, k);
          float h1 = H_BCAST(ha, hb, k + 1);
          a1e = __fmaf_rn(whha[k],     h0, a1e);
          a1o = __fmaf_rn(whha[k + 1], h1, a1o);
          a2e = __fmaf_rn(whhb[k],     h0, a2e);
          a2o = __fmaf_rn(whhb[k + 1], h1, a2o);
        }

        float act1 = gate_act(a1e + a1o, cm, am, ad);
        float act2 = gate_act(a2e + a2o, cm, am, ad);
        float iv = quad_bcast<0>(act1), fv = quad_bcast<1>(act1);
        float gv = quad_bcast<2>(act1), ov = quad_bcast<3>(act1);
        ca = __fmaf_rn(fv, ca, iv * gv);
        ha = ov * fast_tanh(ca);
        iv = quad_bcast<0>(act2); fv = quad_bcast<1>(act2);
        gv = quad_bcast<2>(act2); ov = quad_bcast<3>(act2);
        cb = __fmaf_rn(fv, cb, iv * gv);
        hb = ov * fast_tanh(cb);

        if (g == 0) {
          hbuf[n & 1][k1] = ha;                 // k = 0..15 from lanes 0,4,...,60
          if (k1 < 4) hbuf[n & 1][16 + k1] = hb; // k = 16..19 from lanes 0,4,8,12
        }
      }
      __syncthreads();  // exactly T_SEQ+1 barriers in both waves
    }
  } else {
    // ================= layer-1 consumer wave =================
    float wiha[H_SZ], wihb[H_SZ], whha[H_SZ], whhb[H_SZ];
#pragma unroll
    for (int k = 0; k < H_SZ; ++k) {
      wiha[k] = Wih1[j1 * H_SZ + k];
      wihb[k] = Wih1[j2 * H_SZ + k];
      whha[k] = Whh1[j1 * H_SZ + k];
      whhb[k] = Whh1[j2 * H_SZ + k];
    }
    const float ba = bih1[j1] + bhh1[j1];
    const float bb = bih1[j2] + bhh1[j2];

    float ha = 0.f, ca = 0.f, hb = 0.f, cb = 0.f;
    float* op = out + b * H_SZ;

    for (int n = 0; n <= T_SEQ; ++n) {
      if (n >= 1) {
        const int p = (n - 1) & 1;
        // y = h0(n-1): same-address LDS reads -> broadcast, no conflicts
        const float4 y0 = ((const float4*)hbuf[p])[0];
        const float4 y1 = ((const float4*)hbuf[p])[1];
        const float4 y2 = ((const float4*)hbuf[p])[2];
        const float4 y3 = ((const float4*)hbuf[p])[3];
        const float4 y4 = ((const float4*)hbuf[p])[4];
        const float yv[H_SZ] = {y0.x, y0.y, y0.z, y0.w,
                                y1.x, y1.y, y1.z, y1.w,
                                y2.x, y2.y, y2.z, y2.w,
                                y3.x, y3.y, y3.z, y3.w,
                                y4.x, y4.y, y4.z, y4.w};

        // 8 accumulators: halve the dependent-FMA chain depth
        float ay1e = ba,  ay1o = 0.f, aq1e = 0.f, aq1o = 0.f;
        float ay2e = bb,  ay2o = 0.f, aq2e = 0.f, aq2o = 0.f;
#pragma unroll
        for (int k = 0; k < H_SZ; k += 2) {
          float q0 = H_BCAST(ha, hb, k);
          float q1 = H_BCAST(ha, hb, k + 1);
          ay1e = __fmaf_rn(wiha[k],     yv[k],     ay1e);
          ay1o = __fmaf_rn(wiha[k + 1], yv[k + 1], ay1o);
          ay2e = __fmaf_rn(wihb[k],     yv[k],     ay2e);
          ay2o = __fmaf_rn(wihb[k + 1], yv[k + 1], ay2o);
          aq1e = __fmaf_rn(whha[k],     q0, aq1e);
          aq1o = __fmaf_rn(whha[k + 1], q1, aq1o);
          aq2e = __fmaf_rn(whhb[k],     q0, aq2e);
          aq2o = __fmaf_rn(whhb[k + 1], q1, aq2o);
        }

        float act1 = gate_act((ay1e + ay1o) + (aq1e + aq1o), cm, am, ad);
        float act2 = gate_act((ay2e + ay2o) + (aq2e + aq2o), cm, am, ad);
        float iv = quad_bcast<0>(act1), fv = quad_bcast<1>(act1);
        float gv = quad_bcast<2>(act1), ov = quad_bcast<3>(act1);
        ca = __fmaf_rn(fv, ca, iv * gv);
        ha = ov * fast_tanh(ca);
        iv = quad_bcast<0>(act2); fv = quad_bcast<1>(act2);
        gv = quad_bcast<2>(act2); ov = quad_bcast<3>(act2);
        cb = __fmaf_rn(fv, cb, iv * gv);
        hb = ov * fast_tanh(cb);

        // store out[n-1, b, :]
        if (g == 0) {
          op[k1] = ha;
          if (k1 < 4) op[16 + k1] = hb;
        }
        op += B_SZ * H_SZ;
      }
      __syncthreads();
    }
  }
}

} // namespace

extern "C" void kernel_launch(void* const* d_in, const int* in_sizes, int n_in,
                              void* d_out, int out_size, void* d_ws, size_t ws_size,
                              hipStream_t stream) {
  const float* x    = (const float*)d_in[0];
  const float* Wih0 = (const float*)d_in[1];
  const float* Whh0 = (const float*)d_in[2];
  const float* bih0 = (const float*)d_in[3];
  const float* bhh0 = (const float*)d_in[4];
  const float* Wih1 = (const float*)d_in[5];
  const float* Whh1 = (const float*)d_in[6];
  const float* bih1 = (const float*)d_in[7];
  const float* bhh1 = (const float*)d_in[8];
  float* out = (float*)d_out;

  hipLaunchKernelGGL(lstm2_pipe, dim3(B_SZ), dim3(128), 0, stream,
                     x, Wih0, Whh0, bih0, bhh0, Wih1, Whh1, bih1, bhh1, out);
}

// Round 3
// 787.496 us; speedup vs baseline: 2.5054x; 1.7411x over previous
//
#include <hip/hip_runtime.h>

namespace {

constexpr int T_SEQ = 2048;
constexpr int B_SZ  = 512;
constexpr int C_IN  = 8;
constexpr int H_SZ  = 20;
constexpr int P_LEN = 8;                    // steps per phase (barrier period)
constexpr int N_PH  = T_SEQ / P_LEN;        // 256 producer phases
constexpr float LOG2E = 1.44269504088896340736f;

__device__ __forceinline__ float rlane(float v, int lane) {
  return __int_as_float(__builtin_amdgcn_readlane(__float_as_int(v), lane));
}

template<int S>
__device__ __forceinline__ float quad_bcast(float v) {
  return __int_as_float(__builtin_amdgcn_update_dpp(
      __float_as_int(v), __float_as_int(v), S * 0x55, 0xF, 0xF, true));
}

// slot!=2: sigmoid(a); slot==2: tanh(a). cm has log2e folded in.
__device__ __forceinline__ float gate_act(float a, float cm, float am, float ad) {
  float e = __builtin_amdgcn_exp2f(a * cm);
  float s = __builtin_amdgcn_rcpf(1.0f + e);
  return __fmaf_rn(s, am, ad);
}

__device__ __forceinline__ float fast_tanh(float a) {
  float e = __builtin_amdgcn_exp2f(a * (-2.0f * LOG2E));
  float s = __builtin_amdgcn_rcpf(1.0f + e);
  return __fmaf_rn(s, 2.0f, -1.0f);
}

// h[k] broadcast from lane-distributed registers (set1 at lanes 4k, k<16;
// set2 value for k=16..19 at lanes 4*(k-16)).
#define H_BCAST(ha, hb, k) (((k) < 16) ? rlane((ha), 4 * (k)) : rlane((hb), 4 * ((k) - 16)))

__global__ __attribute__((amdgpu_flat_work_group_size(128, 128),
                          amdgpu_waves_per_eu(1, 1)))
void lstm2_phase(const float* __restrict__ x,
                 const float* __restrict__ Wih0, const float* __restrict__ Whh0,
                 const float* __restrict__ bih0, const float* __restrict__ bhh0,
                 const float* __restrict__ Wih1, const float* __restrict__ Whh1,
                 const float* __restrict__ bih1, const float* __restrict__ bhh1,
                 float* __restrict__ out)
{
  // h0 handoff ring: 16 steps deep (2 phases), row stride 20 floats (80 B, 16-aligned).
  __shared__ __align__(16) float hbuf[2 * P_LEN][H_SZ];
  // x staging: double buffer, one phase each = 8 steps x 8 ch = 64 floats.
  __shared__ __align__(16) float xbuf[2][P_LEN * C_IN];

  const int tid = threadIdx.x;
  const int wv  = tid >> 6;          // 0 = layer-0 wave, 1 = layer-1 wave
  const int l   = tid & 63;
  const int b   = blockIdx.x;
  const int k1  = l >> 2;            // 0..15
  const int g   = l & 3;             // gate slot: 0=i 1=f 2=g 3=o
  const int k2  = 16 + (k1 & 3);     // 16..19 (replicated)
  const int j1  = g * H_SZ + k1;
  const int j2  = g * H_SZ + k2;

  const bool  isg = (g == 2);
  const float cm  = isg ? (-2.0f * LOG2E) : (-LOG2E);
  const float am  = isg ?  2.0f : 1.0f;
  const float ad  = isg ? -1.0f : 0.0f;

  if (wv == 0) {
    // ================= layer-0 producer wave =================
    float wiha[C_IN], wihb[C_IN], whha[H_SZ], whhb[H_SZ];
#pragma unroll
    for (int c = 0; c < C_IN; ++c) {
      wiha[c] = Wih0[j1 * C_IN + c];
      wihb[c] = Wih0[j2 * C_IN + c];
    }
#pragma unroll
    for (int k = 0; k < H_SZ; ++k) {
      whha[k] = Whh0[j1 * H_SZ + k];
      whhb[k] = Whh0[j2 * H_SZ + k];
    }
    const float ba = bih0[j1] + bhh0[j1];
    const float bb = bih0[j2] + bhh0[j2];

    float ha = 0.f, ca = 0.f, hb = 0.f, cb = 0.f;

    // Per-lane x slice: lane l covers step-offset s=l>>3, channel c=l&7.
    // Element index for phase q: (8q + s)*B*C + b*C + c.
    const float* xlane = x + (size_t)(l >> 3) * (B_SZ * C_IN) + b * C_IN + (l & 7);
    const size_t phstride = (size_t)P_LEN * B_SZ * C_IN;

    // Bootstrap: phase 0 slice -> xbuf[0]; phase 1 slice stays in flight.
    float xv0 = xlane[0];
    xbuf[0][l] = xv0;                      // compiler inserts vmcnt wait
    float vnext = xlane[phstride];         // phase 1, committed at end of phase 0

    for (int p = 0; p <= N_PH; ++p) {
      if (p < N_PH) {
        const int buf = p & 1;
        // x for step j=0 of this phase (same-address broadcast reads)
        float4 xa0 = ((const float4*)&xbuf[buf][0])[0];
        float4 xa1 = ((const float4*)&xbuf[buf][0])[1];

        for (int j = 0; j < P_LEN; ++j) {
          const int n = (p << 3) + j;
          const float xv[C_IN] = {xa0.x, xa0.y, xa0.z, xa0.w,
                                  xa1.x, xa1.y, xa1.z, xa1.w};
          if (j + 1 < P_LEN) {             // prefetch next step's x (latency hidden)
            xa0 = ((const float4*)&xbuf[buf][(j + 1) * C_IN])[0];
            xa1 = ((const float4*)&xbuf[buf][(j + 1) * C_IN])[1];
          }

          float a1e = ba, a1o = 0.f, a2e = bb, a2o = 0.f;
#pragma unroll
          for (int c = 0; c < C_IN; c += 2) {
            a1e = __fmaf_rn(wiha[c],     xv[c],     a1e);
            a1o = __fmaf_rn(wiha[c + 1], xv[c + 1], a1o);
            a2e = __fmaf_rn(wihb[c],     xv[c],     a2e);
            a2o = __fmaf_rn(wihb[c + 1], xv[c + 1], a2o);
          }
#pragma unroll
          for (int k = 0; k < H_SZ; k += 2) {
            float h0 = H_BCAST(ha, hb, k);
            float h1 = H_BCAST(ha, hb, k + 1);
            a1e = __fmaf_rn(whha[k],     h0, a1e);
            a1o = __fmaf_rn(whha[k + 1], h1, a1o);
            a2e = __fmaf_rn(whhb[k],     h0, a2e);
            a2o = __fmaf_rn(whhb[k + 1], h1, a2o);
          }

          float act1 = gate_act(a1e + a1o, cm, am, ad);
          float act2 = gate_act(a2e + a2o, cm, am, ad);
          float iv = quad_bcast<0>(act1), fv = quad_bcast<1>(act1);
          float gv = quad_bcast<2>(act1), ov = quad_bcast<3>(act1);
          ca = __fmaf_rn(fv, ca, iv * gv);
          ha = ov * fast_tanh(ca);
          iv = quad_bcast<0>(act2); fv = quad_bcast<1>(act2);
          gv = quad_bcast<2>(act2); ov = quad_bcast<3>(act2);
          cb = __fmaf_rn(fv, cb, iv * gv);
          hb = ov * fast_tanh(cb);

          const int slot = n & (2 * P_LEN - 1);
          if (g == 0) {
            hbuf[slot][k1] = ha;
            if (k1 < 4) hbuf[slot][16 + k1] = hb;
          }
        }

        // Commit next phase's x (load has been in flight ~8 steps) and
        // issue the load for phase p+2.
        if (p + 1 < N_PH) xbuf[(p + 1) & 1][l] = vnext;
        if (p + 2 < N_PH) vnext = xlane[(size_t)(p + 2) * phstride];
      }
      __syncthreads();   // once per phase: 257 barriers total, both waves
    }
  } else {
    // ================= layer-1 consumer wave (lags one phase) =================
    float wiha[H_SZ], wihb[H_SZ], whha[H_SZ], whhb[H_SZ];
#pragma unroll
    for (int k = 0; k < H_SZ; ++k) {
      wiha[k] = Wih1[j1 * H_SZ + k];
      wihb[k] = Wih1[j2 * H_SZ + k];
      whha[k] = Whh1[j1 * H_SZ + k];
      whhb[k] = Whh1[j2 * H_SZ + k];
    }
    const float ba = bih1[j1] + bhh1[j1];
    const float bb = bih1[j2] + bhh1[j2];

    float ha = 0.f, ca = 0.f, hb = 0.f, cb = 0.f;
    float* op = out + b * H_SZ;

    for (int p = 0; p <= N_PH; ++p) {
      if (p >= 1) {
        for (int j = 0; j < P_LEN; ++j) {
          const int n = ((p - 1) << 3) + j;
          const int slot = n & (2 * P_LEN - 1);
          // y = h0(n): same-address LDS reads -> broadcast
          const float4 y0 = ((const float4*)hbuf[slot])[0];
          const float4 y1 = ((const float4*)hbuf[slot])[1];
          const float4 y2 = ((const float4*)hbuf[slot])[2];
          const float4 y3 = ((const float4*)hbuf[slot])[3];
          const float4 y4 = ((const float4*)hbuf[slot])[4];
          const float yv[H_SZ] = {y0.x, y0.y, y0.z, y0.w,
                                  y1.x, y1.y, y1.z, y1.w,
                                  y2.x, y2.y, y2.z, y2.w,
                                  y3.x, y3.y, y3.z, y3.w,
                                  y4.x, y4.y, y4.z, y4.w};

          float ay1e = ba,  ay1o = 0.f, aq1e = 0.f, aq1o = 0.f;
          float ay2e = bb,  ay2o = 0.f, aq2e = 0.f, aq2o = 0.f;
#pragma unroll
          for (int k = 0; k < H_SZ; k += 2) {
            float q0 = H_BCAST(ha, hb, k);
            float q1 = H_BCAST(ha, hb, k + 1);
            ay1e = __fmaf_rn(wiha[k],     yv[k],     ay1e);
            ay1o = __fmaf_rn(wiha[k + 1], yv[k + 1], ay1o);
            ay2e = __fmaf_rn(wihb[k],     yv[k],     ay2e);
            ay2o = __fmaf_rn(wihb[k + 1], yv[k + 1], ay2o);
            aq1e = __fmaf_rn(whha[k],     q0, aq1e);
            aq1o = __fmaf_rn(whha[k + 1], q1, aq1o);
            aq2e = __fmaf_rn(whhb[k],     q0, aq2e);
            aq2o = __fmaf_rn(whhb[k + 1], q1, aq2o);
          }

          float act1 = gate_act((ay1e + ay1o) + (aq1e + aq1o), cm, am, ad);
          float act2 = gate_act((ay2e + ay2o) + (aq2e + aq2o), cm, am, ad);
          float iv = quad_bcast<0>(act1), fv = quad_bcast<1>(act1);
          float gv = quad_bcast<2>(act1), ov = quad_bcast<3>(act1);
          ca = __fmaf_rn(fv, ca, iv * gv);
          ha = ov * fast_tanh(ca);
          iv = quad_bcast<0>(act2); fv = quad_bcast<1>(act2);
          gv = quad_bcast<2>(act2); ov = quad_bcast<3>(act2);
          cb = __fmaf_rn(fv, cb, iv * gv);
          hb = ov * fast_tanh(cb);

          if (g == 0) {
            op[k1] = ha;
            if (k1 < 4) op[16 + k1] = hb;
          }
          op += B_SZ * H_SZ;
        }
      }
      __syncthreads();
    }
  }
}

} // namespace

extern "C" void kernel_launch(void* const* d_in, const int* in_sizes, int n_in,
                              void* d_out, int out_size, void* d_ws, size_t ws_size,
                              hipStream_t stream) {
  const float* x    = (const float*)d_in[0];
  const float* Wih0 = (const float*)d_in[1];
  const float* Whh0 = (const float*)d_in[2];
  const float* bih0 = (const float*)d_in[3];
  const float* bhh0 = (const float*)d_in[4];
  const float* Wih1 = (const float*)d_in[5];
  const float* Whh1 = (const float*)d_in[6];
  const float* bih1 = (const float*)d_in[7];
  const float* bhh1 = (const float*)d_in[8];
  float* out = (float*)d_out;

  hipLaunchKernelGGL(lstm2_phase, dim3(B_SZ), dim3(128), 0, stream,
                     x, Wih0, Whh0, bih0, bhh0, Wih1, Whh1, bih1, bhh1, out);
}

// Round 4
// 706.767 us; speedup vs baseline: 2.7915x; 1.1142x over previous
//
#include <hip/hip_runtime.h>

namespace {

typedef float v2f __attribute__((ext_vector_type(2)));

constexpr int T_SEQ = 2048;
constexpr int B_SZ  = 512;
constexpr int C_IN  = 8;
constexpr int H_SZ  = 20;
constexpr int P_LEN = 16;                 // steps per phase (barrier period)
constexpr int N_PH  = T_SEQ / P_LEN;      // 128 phases
constexpr int RING  = 2 * P_LEN;          // 32-slot h0 handoff ring
constexpr float LOG2E = 1.44269504088896340736f;

__device__ __forceinline__ float rlane(float v, int lane) {
  return __int_as_float(__builtin_amdgcn_readlane(__float_as_int(v), lane));
}

template<int S>
__device__ __forceinline__ float quad_bcast(float v) {
  return __int_as_float(__builtin_amdgcn_update_dpp(
      __float_as_int(v), __float_as_int(v), S * 0x55, 0xF, 0xF, true));
}

__device__ __forceinline__ v2f fma2(v2f a, v2f b, v2f c) {
  return __builtin_elementwise_fma(a, b, c);   // -> v_pk_fma_f32
}
__device__ __forceinline__ v2f splat2(float s) { v2f r; r.x = s; r.y = s; return r; }
__device__ __forceinline__ v2f zero2() { v2f r; r.x = 0.f; r.y = 0.f; return r; }

// Elementwise activation on both gate sets: sigmoid (g!=2) / tanh (g==2).
// cm has log2e pre-folded; tanh(x) = 2*sigmoid(2x)-1.
__device__ __forceinline__ v2f act2(v2f a, float cm, float am, float ad) {
  float ex = __builtin_amdgcn_exp2f(a.x * cm);
  float ey = __builtin_amdgcn_exp2f(a.y * cm);
  float sx = __builtin_amdgcn_rcpf(1.0f + ex);
  float sy = __builtin_amdgcn_rcpf(1.0f + ey);
  v2f r; r.x = __fmaf_rn(sx, am, ad); r.y = __fmaf_rn(sy, am, ad);
  return r;
}

__device__ __forceinline__ float fast_tanh(float a) {
  float e = __builtin_amdgcn_exp2f(a * (-2.0f * LOG2E));
  float s = __builtin_amdgcn_rcpf(1.0f + e);
  return __fmaf_rn(s, 2.0f, -1.0f);
}

// h[k] broadcast from lane-distributed regs (set1 at lanes 4k, k<16;
// set2 value for k=16..19 at lanes 4*(k-16)).
#define H_BCAST(ha, hb, k) (((k) < 16) ? rlane((ha), 4 * (k)) : rlane((hb), 4 * ((k) - 16)))

__global__ __attribute__((amdgpu_flat_work_group_size(128, 128),
                          amdgpu_waves_per_eu(1, 1)))
void lstm2_pk(const float* __restrict__ x,
              const float* __restrict__ Wih0, const float* __restrict__ Whh0,
              const float* __restrict__ bih0, const float* __restrict__ bhh0,
              const float* __restrict__ Wih1, const float* __restrict__ Whh1,
              const float* __restrict__ bih1, const float* __restrict__ bhh1,
              float* __restrict__ out)
{
  // h0 handoff ring: 32 steps (2 phases), 20 floats per slot (80 B, 16-aligned).
  __shared__ __align__(16) float hbuf[RING][H_SZ];
  // x staging: double buffer, 16 steps x 8 ch = 128 floats per phase.
  __shared__ __align__(16) float xbuf[2][P_LEN * C_IN];

  const int tid = threadIdx.x;
  const int wv  = tid >> 6;          // 0 = layer-0 wave, 1 = layer-1 wave
  const int l   = tid & 63;
  const int b   = blockIdx.x;
  const int k1  = l >> 2;            // 0..15
  const int g   = l & 3;             // gate slot: 0=i 1=f 2=g 3=o
  const int k2  = 16 + (k1 & 3);     // 16..19 (replicated)
  const int j1  = g * H_SZ + k1;
  const int j2  = g * H_SZ + k2;

  const bool  isg = (g == 2);
  const float cm  = isg ? (-2.0f * LOG2E) : (-LOG2E);
  const float am  = isg ?  2.0f : 1.0f;
  const float ad  = isg ? -1.0f : 0.0f;

  if (wv == 0) {
    // ================= layer-0 producer wave =================
    v2f wx1[C_IN / 2], wx2[C_IN / 2];  // Wih0 rows j1/j2, k-packed
    v2f wh[H_SZ];                      // {Whh0[j1][k], Whh0[j2][k]} gate-set packed
#pragma unroll
    for (int t = 0; t < C_IN / 2; ++t) {
      wx1[t].x = Wih0[j1 * C_IN + 2 * t]; wx1[t].y = Wih0[j1 * C_IN + 2 * t + 1];
      wx2[t].x = Wih0[j2 * C_IN + 2 * t]; wx2[t].y = Wih0[j2 * C_IN + 2 * t + 1];
    }
#pragma unroll
    for (int k = 0; k < H_SZ; ++k) {
      wh[k].x = Whh0[j1 * H_SZ + k]; wh[k].y = Whh0[j2 * H_SZ + k];
    }
    v2f bias2; bias2.x = bih0[j1] + bhh0[j1]; bias2.y = bih0[j2] + bhh0[j2];

    float ha = 0.f, ca = 0.f, hb = 0.f, cb = 0.f;

    // Per-lane x slice: element e in [0,128) of a phase -> step e>>3, channel e&7.
    // Lane l covers e = l and e = l+64 (the latter is +8 steps).
    const float* xl = x + (size_t)(l >> 3) * (B_SZ * C_IN) + b * C_IN + (l & 7);
    const size_t halfph = (size_t)8 * B_SZ * C_IN;
    const size_t phstr  = (size_t)P_LEN * B_SZ * C_IN;

    // Bootstrap: phase 0 committed now; phase 1 stays in flight a whole phase.
    {
      float v0 = xl[0], v1 = xl[halfph];
      xbuf[0][l] = v0; xbuf[0][64 + l] = v1;
    }
    float n0 = xl[phstr], n1 = xl[phstr + halfph];

    for (int p = 0; p <= N_PH; ++p) {
      if (p < N_PH) {
        const int buf = p & 1;
        float4 xc0 = ((const float4*)&xbuf[buf][0])[0];
        float4 xc1 = ((const float4*)&xbuf[buf][0])[1];
        for (int j = 0; j < P_LEN; ++j) {
          const int n = p * P_LEN + j;
          v2f xp[4];
          xp[0].x = xc0.x; xp[0].y = xc0.y; xp[1].x = xc0.z; xp[1].y = xc0.w;
          xp[2].x = xc1.x; xp[2].y = xc1.y; xp[3].x = xc1.z; xp[3].y = xc1.w;
          if (j + 1 < P_LEN) {           // one-step-ahead x prefetch (LDS bcast)
            xc0 = ((const float4*)&xbuf[buf][(j + 1) * C_IN])[0];
            xc1 = ((const float4*)&xbuf[buf][(j + 1) * C_IN])[1];
          }

          // Recurrent dot, gate-set packed, 2 accs (chain depth 10).
          v2f A0 = bias2, A1 = zero2();
#pragma unroll
          for (int k = 0; k < H_SZ; k += 2) {
            float h0 = H_BCAST(ha, hb, k);
            float h1 = H_BCAST(ha, hb, k + 1);
            A0 = fma2(wh[k],     splat2(h0), A0);
            A1 = fma2(wh[k + 1], splat2(h1), A1);
          }
          // Input dot, k-packed per gate set.
          v2f X1 = zero2(), X2 = zero2();
#pragma unroll
          for (int t = 0; t < C_IN / 2; ++t) {
            X1 = fma2(wx1[t], xp[t], X1);
            X2 = fma2(wx2[t], xp[t], X2);
          }
          v2f A = A0 + A1;
          A.x += X1.x + X1.y;
          A.y += X2.x + X2.y;

          v2f act = act2(A, cm, am, ad);
          float iv = quad_bcast<0>(act.x), fv = quad_bcast<1>(act.x);
          float gv = quad_bcast<2>(act.x), ov = quad_bcast<3>(act.x);
          ca = __fmaf_rn(fv, ca, iv * gv);
          ha = ov * fast_tanh(ca);
          iv = quad_bcast<0>(act.y); fv = quad_bcast<1>(act.y);
          gv = quad_bcast<2>(act.y); ov = quad_bcast<3>(act.y);
          cb = __fmaf_rn(fv, cb, iv * gv);
          hb = ov * fast_tanh(cb);

          const int slot = n & (RING - 1);
          if (g == 0) {
            hbuf[slot][k1] = ha;
            if (k1 < 4) hbuf[slot][16 + k1] = hb;
          }
        }
        // Commit next phase's x (in flight ~16 steps); issue load for p+2.
        if (p + 1 < N_PH) { xbuf[(p + 1) & 1][l] = n0; xbuf[(p + 1) & 1][64 + l] = n1; }
        if (p + 2 < N_PH) {
          n0 = xl[(size_t)(p + 2) * phstr];
          n1 = xl[(size_t)(p + 2) * phstr + halfph];
        }
      }
      __syncthreads();   // 129 barriers total, both waves
    }
  } else {
    // ================= layer-1 consumer wave (lags one phase) =================
    v2f wy1[H_SZ / 2], wy2[H_SZ / 2];  // Wih1 rows j1/j2, k-packed
    v2f wq[H_SZ];                      // {Whh1[j1][k], Whh1[j2][k]} gate-set packed
#pragma unroll
    for (int t = 0; t < H_SZ / 2; ++t) {
      wy1[t].x = Wih1[j1 * H_SZ + 2 * t]; wy1[t].y = Wih1[j1 * H_SZ + 2 * t + 1];
      wy2[t].x = Wih1[j2 * H_SZ + 2 * t]; wy2[t].y = Wih1[j2 * H_SZ + 2 * t + 1];
    }
#pragma unroll
    for (int k = 0; k < H_SZ; ++k) {
      wq[k].x = Whh1[j1 * H_SZ + k]; wq[k].y = Whh1[j2 * H_SZ + k];
    }
    v2f bias2; bias2.x = bih1[j1] + bhh1[j1]; bias2.y = bih1[j2] + bhh1[j2];

    float ha = 0.f, ca = 0.f, hb = 0.f, cb = 0.f;
    float* op = out + b * H_SZ;

    auto stepW1 = [&](int n, const float4 (&yq)[5]) {
      v2f yp[H_SZ / 2];
      yp[0].x = yq[0].x; yp[0].y = yq[0].y; yp[1].x = yq[0].z; yp[1].y = yq[0].w;
      yp[2].x = yq[1].x; yp[2].y = yq[1].y; yp[3].x = yq[1].z; yp[3].y = yq[1].w;
      yp[4].x = yq[2].x; yp[4].y = yq[2].y; yp[5].x = yq[2].z; yp[5].y = yq[2].w;
      yp[6].x = yq[3].x; yp[6].y = yq[3].y; yp[7].x = yq[3].z; yp[7].y = yq[3].w;
      yp[8].x = yq[4].x; yp[8].y = yq[4].y; yp[9].x = yq[4].z; yp[9].y = yq[4].w;

      // y-stream: k-packed per gate set, 2 accs each (chain depth 5).
      v2f Y1a = zero2(), Y1b = zero2(), Y2a = zero2(), Y2b = zero2();
#pragma unroll
      for (int t = 0; t < H_SZ / 2; t += 2) {
        Y1a = fma2(wy1[t],     yp[t],     Y1a);
        Y2a = fma2(wy2[t],     yp[t],     Y2a);
        Y1b = fma2(wy1[t + 1], yp[t + 1], Y1b);
        Y2b = fma2(wy2[t + 1], yp[t + 1], Y2b);
      }
      // q-stream (h1 recurrence): gate-set packed, 2 accs (chain depth 10).
      v2f Q0 = bias2, Q1 = zero2();
#pragma unroll
      for (int k = 0; k < H_SZ; k += 2) {
        float q0 = H_BCAST(ha, hb, k);
        float q1 = H_BCAST(ha, hb, k + 1);
        Q0 = fma2(wq[k],     splat2(q0), Q0);
        Q1 = fma2(wq[k + 1], splat2(q1), Q1);
      }
      v2f A = Q0 + Q1;
      v2f Y1 = Y1a + Y1b, Y2 = Y2a + Y2b;
      A.x += Y1.x + Y1.y;
      A.y += Y2.x + Y2.y;

      v2f act = act2(A, cm, am, ad);
      float iv = quad_bcast<0>(act.x), fv = quad_bcast<1>(act.x);
      float gv = quad_bcast<2>(act.x), ov = quad_bcast<3>(act.x);
      ca = __fmaf_rn(fv, ca, iv * gv);
      ha = ov * fast_tanh(ca);
      iv = quad_bcast<0>(act.y); fv = quad_bcast<1>(act.y);
      gv = quad_bcast<2>(act.y); ov = quad_bcast<3>(act.y);
      cb = __fmaf_rn(fv, cb, iv * gv);
      hb = ov * fast_tanh(cb);

      if (g == 0) {
        op[k1] = ha;
        if (k1 < 4) op[16 + k1] = hb;
      }
      op += B_SZ * H_SZ;
    };

    for (int p = 0; p <= N_PH; ++p) {
      if (p >= 1) {
        const int base = (p - 1) * P_LEN;
        float4 yA[5], yB[5];
        {
          const float4* s = (const float4*)hbuf[base & (RING - 1)];
          yA[0] = s[0]; yA[1] = s[1]; yA[2] = s[2]; yA[3] = s[3]; yA[4] = s[4];
        }
        {
          const float4* s = (const float4*)hbuf[(base + 1) & (RING - 1)];
          yB[0] = s[0]; yB[1] = s[1]; yB[2] = s[2]; yB[3] = s[3]; yB[4] = s[4];
        }
        for (int jj = 0; jj < P_LEN; jj += 2) {
          stepW1(base + jj, yA);
          if (jj + 2 < P_LEN) {        // reload issued now, consumed next-next step
            const float4* s = (const float4*)hbuf[(base + jj + 2) & (RING - 1)];
            yA[0] = s[0]; yA[1] = s[1]; yA[2] = s[2]; yA[3] = s[3]; yA[4] = s[4];
          }
          stepW1(base + jj + 1, yB);
          if (jj + 3 < P_LEN) {
            const float4* s = (const float4*)hbuf[(base + jj + 3) & (RING - 1)];
            yB[0] = s[0]; yB[1] = s[1]; yB[2] = s[2]; yB[3] = s[3]; yB[4] = s[4];
          }
        }
      }
      __syncthreads();
    }
  }
}

} // namespace

extern "C" void kernel_launch(void* const* d_in, const int* in_sizes, int n_in,
                              void* d_out, int out_size, void* d_ws, size_t ws_size,
                              hipStream_t stream) {
  const float* x    = (const float*)d_in[0];
  const float* Wih0 = (const float*)d_in[1];
  const float* Whh0 = (const float*)d_in[2];
  const float* bih0 = (const float*)d_in[3];
  const float* bhh0 = (const float*)d_in[4];
  const float* Wih1 = (const float*)d_in[5];
  const float* Whh1 = (const float*)d_in[6];
  const float* bih1 = (const float*)d_in[7];
  const float* bhh1 = (const float*)d_in[8];
  float* out = (float*)d_out;

  hipLaunchKernelGGL(lstm2_pk, dim3(B_SZ), dim3(128), 0, stream,
                     x, Wih0, Whh0, bih0, bhh0, Wih1, Whh1, bih1, bhh1, out);
}